// Round 1
// baseline (462.234 us; speedup 1.0000x reference)
//
#include <hip/hip_runtime.h>
#include <hip/hip_fp16.h>

typedef _Float16 f16;
typedef _Float16 f16x8 __attribute__((ext_vector_type(8)));
typedef _Float16 f16x4 __attribute__((ext_vector_type(4)));
typedef float    f32x4 __attribute__((ext_vector_type(4)));

#define SEQ      4096
#define DEMB     2048
#define BM       128
#define BN       128
#define BK       32
#define SCALE_QK 0.08838834764831845f   // 1/sqrt(128)

#define GAS __attribute__((address_space(1)))
#define LAS __attribute__((address_space(3)))

// async global->LDS, 16B per lane. LDS dest = wave-uniform base + lane*16.
__device__ __forceinline__ void load_lds16(const f16* g, f16* l) {
    __builtin_amdgcn_global_load_lds((const GAS void*)g, (LAS void*)l, 16, 0, 0);
}

// ---------------------------------------------------------------------------
// fp32 -> fp16 elementwise convert (x). n divisible by 1024.
// ---------------------------------------------------------------------------
__global__ __launch_bounds__(256) void cvt_f16(const float* __restrict__ in,
                                               f16* __restrict__ out, int n) {
    int i = (blockIdx.x * 256 + threadIdx.x) * 4;
    if (i >= n) return;
    float4 v = *(const float4*)&in[i];
    f16x4 o; o[0] = (f16)v.x; o[1] = (f16)v.y; o[2] = (f16)v.z; o[3] = (f16)v.w;
    *(f16x4*)&out[i] = o;
}

// ---------------------------------------------------------------------------
// fp32 [R][C] -> fp16 [C][R] tiled transpose+convert (weights).
// ---------------------------------------------------------------------------
__global__ __launch_bounds__(256) void transpose_cvt(const float* __restrict__ in,
                                                     f16* __restrict__ out,
                                                     int R, int C) {
    __shared__ f16 tile[64][72];               // 72: break power-of-2 stride
    const int c0 = blockIdx.x * 64;
    const int r0 = blockIdx.y * 64;
    const int tx = threadIdx.x & 63;
    const int ty = threadIdx.x >> 6;
    for (int rr = ty; rr < 64; rr += 4)
        tile[tx][rr] = (f16)in[(size_t)(r0 + rr) * C + c0 + tx];
    __syncthreads();
    for (int cc = ty; cc < 64; cc += 4)
        out[(size_t)(c0 + cc) * R + r0 + tx] = tile[cc][tx];
}

// ---------------------------------------------------------------------------
// Generic C = A @ B (+bias), A:[M][K] f16 row-major, BT:[N][K] f16 row-major.
// 128x128 tile, BK=32, 4 waves each owning 64x64 (4x4 fragments of 16x16x32).
// MODE 0: f16 out [M][N], +bias          (Q, K)
// MODE 1: f16 out TRANSPOSED [N][M], +bias (V -> V^T for PV's B^T operand)
// MODE 2: f32 out [M][N], +bias          (final output)
// MODE 3: f16 out [M][N] * scale, skip tiles fully above diagonal (scores)
// MODE 4: f16 out [M][N], K-loop limited to (bm+1)*BM (PV, causal)
// ---------------------------------------------------------------------------
template <int MODE>
__global__ __launch_bounds__(256)
void gemm_bt(const f16* __restrict__ A, const f16* __restrict__ BT,
             const float* __restrict__ bias, void* __restrict__ Cout,
             int M, int N, int K, float scale) {
    __shared__ f16 As[BM * BK];
    __shared__ f16 Bs[BN * BK];

    const int bn = blockIdx.x, bm = blockIdx.y;
    if (MODE == 3 && bn > bm) return;          // fully-masked tile
    const int m0 = bm * BM, n0 = bn * BN;
    const int kEnd = (MODE == 4) ? ((bm + 1) * BM) : K;

    const int t    = threadIdx.x;
    const int lane = t & 63;
    const int wid  = t >> 6;
    const int wr   = wid >> 1, wc = wid & 1;   // wave -> 64x64 quadrant

    f32x4 acc[4][4] = {};

    const int srow = lane >> 2;                // staging: row within 16-row slab
    const int scol = (lane & 3) * 8;           // staging: k offset (8 f16 = 16B)
    const int fr   = lane & 15;                // fragment row/col
    const int k8   = (lane >> 4) * 8;          // fragment k base (contiguous 8)

    for (int k0 = 0; k0 < kEnd; k0 += BK) {
#pragma unroll
        for (int i = 0; i < 2; ++i) {
            const int r0 = i * 64 + wid * 16;  // wave-uniform 16-row slab
            load_lds16(A  + (size_t)(m0 + r0 + srow) * K + k0 + scol, As + r0 * BK);
            load_lds16(BT + (size_t)(n0 + r0 + srow) * K + k0 + scol, Bs + r0 * BK);
        }
        __syncthreads();

        f16x8 af[4], bf[4];
#pragma unroll
        for (int m = 0; m < 4; ++m)
            af[m] = *(const f16x8*)&As[(wr * 64 + m * 16 + fr) * BK + k8];
#pragma unroll
        for (int n = 0; n < 4; ++n)
            bf[n] = *(const f16x8*)&Bs[(wc * 64 + n * 16 + fr) * BK + k8];
#pragma unroll
        for (int m = 0; m < 4; ++m)
#pragma unroll
            for (int n = 0; n < 4; ++n)
                acc[m][n] = __builtin_amdgcn_mfma_f32_16x16x32_f16(
                    af[m], bf[n], acc[m][n], 0, 0, 0);
        __syncthreads();
    }

    // C/D layout (verified m89/m91): col = lane&15, row = (lane>>4)*4 + reg.
    const int rq = (lane >> 4) * 4;
#pragma unroll
    for (int m = 0; m < 4; ++m) {
        const int rowb = m0 + wr * 64 + m * 16 + rq;
#pragma unroll
        for (int n = 0; n < 4; ++n) {
            const int col = n0 + wc * 64 + n * 16 + fr;
            if (MODE == 0) {
                f16* out = (f16*)Cout;
                const float bv = bias[col];
#pragma unroll
                for (int r = 0; r < 4; ++r)
                    out[(size_t)(rowb + r) * N + col] = (f16)(acc[m][n][r] + bv);
            } else if (MODE == 1) {
                f16* out = (f16*)Cout;
                const float bv = bias[col];
                f16x4 v;
#pragma unroll
                for (int r = 0; r < 4; ++r) v[r] = (f16)(acc[m][n][r] + bv);
                *(f16x4*)&out[(size_t)col * M + rowb] = v;  // transposed store
            } else if (MODE == 2) {
                float* out = (float*)Cout;
                const float bv = bias[col];
#pragma unroll
                for (int r = 0; r < 4; ++r)
                    out[(size_t)(rowb + r) * N + col] = acc[m][n][r] + bv;
            } else if (MODE == 3) {
                f16* out = (f16*)Cout;
#pragma unroll
                for (int r = 0; r < 4; ++r)
                    out[(size_t)(rowb + r) * N + col] = (f16)(acc[m][n][r] * scale);
            } else {  // MODE 4
                f16* out = (f16*)Cout;
#pragma unroll
                for (int r = 0; r < 4; ++r)
                    out[(size_t)(rowb + r) * N + col] = (f16)acc[m][n][r];
            }
        }
    }
}

// ---------------------------------------------------------------------------
// In-place causal row softmax on S:[SEQ][SEQ] f16. Row i: valid j in [0,i].
// Writes zeros for j in (i, roundup(i+1,128)) so the PV GEMM's padded K-loop
// reads only defined data.
// ---------------------------------------------------------------------------
__global__ __launch_bounds__(256) void softmax_causal(f16* __restrict__ S) {
    const int i  = blockIdx.x;
    const int L  = i + 1;
    const int Lp = ((i >> 7) + 1) << 7;        // band-padded length
    f16* row = S + (size_t)i * SEQ;
    const int t = threadIdx.x;

    __shared__ float red[8];

    float mx = -3.0e38f;
    for (int j = t; j < L; j += 256) mx = fmaxf(mx, (float)row[j]);
#pragma unroll
    for (int o = 32; o > 0; o >>= 1) mx = fmaxf(mx, __shfl_xor(mx, o));
    if ((t & 63) == 0) red[t >> 6] = mx;
    __syncthreads();
    mx = fmaxf(fmaxf(red[0], red[1]), fmaxf(red[2], red[3]));

    float sm = 0.f;
    for (int j = t; j < L; j += 256) sm += __expf((float)row[j] - mx);
#pragma unroll
    for (int o = 32; o > 0; o >>= 1) sm += __shfl_xor(sm, o);
    if ((t & 63) == 0) red[4 + (t >> 6)] = sm;
    __syncthreads();
    const float inv = 1.f / (red[4] + red[5] + red[6] + red[7]);

    for (int j = t; j < Lp; j += 256) {
        const float p = (j < L) ? __expf((float)row[j] - mx) * inv : 0.f;
        row[j] = (f16)p;
    }
}

// ---------------------------------------------------------------------------
extern "C" void kernel_launch(void* const* d_in, const int* in_sizes, int n_in,
                              void* d_out, int out_size, void* d_ws, size_t ws_size,
                              hipStream_t stream) {
    const float* x  = (const float*)d_in[0];
    const float* WQ = (const float*)d_in[1];
    const float* WK = (const float*)d_in[2];
    const float* WV = (const float*)d_in[3];
    const float* WO = (const float*)d_in[4];
    const float* bQ = (const float*)d_in[5];
    const float* bK = (const float*)d_in[6];
    const float* bV = (const float*)d_in[7];
    const float* bO = (const float*)d_in[8];
    float* out = (float*)d_out;

    // workspace layout (~109 MB)
    char* w = (char*)d_ws;
    f16* x16  = (f16*)w; w += (size_t)SEQ * DEMB * 2;   // 16.8 MB (reused for attn)
    f16* q16  = (f16*)w; w += (size_t)SEQ * DEMB * 2;
    f16* k16  = (f16*)w; w += (size_t)SEQ * DEMB * 2;
    f16* vt16 = (f16*)w; w += (size_t)SEQ * DEMB * 2;   // V^T [DEMB][SEQ]
    f16* wt   = (f16*)w; w += (size_t)DEMB * DEMB * 2;  // W^T scratch, reused 4x
    f16* sb   = (f16*)w; w += (size_t)SEQ * SEQ * 2;    // scores -> P in place
    f16* attn16 = x16;  // x16 dead after V projection

    const dim3 blk(256);
    const dim3 gProj(DEMB / BN, SEQ / BM);   // (16, 32)
    const dim3 gScore(SEQ / BN, SEQ / BM);   // (32, 32)
    const dim3 gW(DEMB / 64, DEMB / 64);

    cvt_f16<<<(SEQ * DEMB) / 1024, blk, 0, stream>>>(x, x16, SEQ * DEMB);

    transpose_cvt<<<gW, blk, 0, stream>>>(WQ, wt, DEMB, DEMB);
    gemm_bt<0><<<gProj, blk, 0, stream>>>(x16, wt, bQ, q16, SEQ, DEMB, DEMB, 1.f);

    transpose_cvt<<<gW, blk, 0, stream>>>(WK, wt, DEMB, DEMB);
    gemm_bt<0><<<gProj, blk, 0, stream>>>(x16, wt, bK, k16, SEQ, DEMB, DEMB, 1.f);

    transpose_cvt<<<gW, blk, 0, stream>>>(WV, wt, DEMB, DEMB);
    gemm_bt<1><<<gProj, blk, 0, stream>>>(x16, wt, bV, vt16, SEQ, DEMB, DEMB, 1.f);

    // scores = q @ k^T * 1/sqrt(128); skip fully-above-diagonal tiles
    gemm_bt<3><<<gScore, blk, 0, stream>>>(q16, k16, nullptr, sb, SEQ, SEQ, DEMB,
                                           SCALE_QK);
    softmax_causal<<<SEQ, blk, 0, stream>>>(sb);

    // attn = P @ V   (B^T = V^T), causal K-limit per row band
    gemm_bt<4><<<gProj, blk, 0, stream>>>(sb, vt16, nullptr, attn16, SEQ, DEMB,
                                          SEQ, 1.f);

    transpose_cvt<<<gW, blk, 0, stream>>>(WO, wt, DEMB, DEMB);
    gemm_bt<2><<<gProj, blk, 0, stream>>>(attn16, wt, bO, out, SEQ, DEMB, DEMB,
                                          1.f);
}

// Round 2
// 420.428 us; speedup vs baseline: 1.0994x; 1.0994x over previous
//
#include <hip/hip_runtime.h>
#include <hip/hip_fp16.h>

typedef _Float16 f16;
typedef _Float16 f16x8 __attribute__((ext_vector_type(8)));
typedef float    f32x4 __attribute__((ext_vector_type(4)));

#define SEQ      4096
#define DEMB     2048
#define SCALE_QK 0.08838834764831845f   // 1/sqrt(128)

#define GAS __attribute__((address_space(1)))
#define LAS __attribute__((address_space(3)))

// async global->LDS, 16B/lane. LDS dest = wave-uniform base + lane*16 (m104).
__device__ __forceinline__ void load_lds16(const f16* g, f16* l) {
    __builtin_amdgcn_global_load_lds((const GAS void*)g, (LAS void*)l, 16, 0, 0);
}

// st_16x32 swizzled LDS read (T2): byte ^= ((byte>>9)&1)<<5, involution.
__device__ __forceinline__ f16x8 ldsr(const f16* base, int byteoff) {
    byteoff ^= ((byteoff >> 9) & 1) << 5;
    return *(const f16x8*)((const char*)base + byteoff);
}

// Stage one half-tile [128 rows][64 f16] (16KB) into LDS (linear dest,
// inverse-swizzled per-lane SOURCE per rule #21). 512 threads, 2 issues.
__device__ __forceinline__ void stage_half(const f16* __restrict__ src, int ldk,
                                           f16* ldsdst, int tid) {
#pragma unroll
    for (int s = 0; s < 2; ++s) {
        const int o   = s * 8192 + tid * 16;           // linear byte off in half
        const int osw = o ^ (((o >> 9) & 1) << 5);     // pre-swizzled source
        load_lds16(src + (size_t)(osw >> 7) * ldk + ((osw & 127) >> 1),
                   ldsdst + (s * 8192 + (tid >> 6) * 1024) / 2);
    }
}

// ---------------------------------------------------------------------------
// fp32 -> fp16 convert (x)
// ---------------------------------------------------------------------------
__global__ __launch_bounds__(256) void cvt_f16(const float* __restrict__ in,
                                               f16* __restrict__ out, int n) {
    int i = (blockIdx.x * 256 + threadIdx.x) * 4;
    if (i >= n) return;
    float4 v = *(const float4*)&in[i];
    f16 o0 = (f16)v.x, o1 = (f16)v.y, o2 = (f16)v.z, o3 = (f16)v.w;
    f16* p = &out[i];
    p[0] = o0; p[1] = o1; p[2] = o2; p[3] = o3;
}

// ---------------------------------------------------------------------------
// All four weights: fp32 [2048][2048] -> fp16 transposed. z selects matrix.
// z<3 -> wqkvt (concat W_Q^T, W_K^T, W_V^T), z==3 -> wot.
// ---------------------------------------------------------------------------
__global__ __launch_bounds__(256) void transpose_cvt4(
        const float* __restrict__ WQ, const float* __restrict__ WK,
        const float* __restrict__ WV, const float* __restrict__ WO,
        f16* __restrict__ wqkvt, f16* __restrict__ wot) {
    __shared__ f16 tile[64][72];
    const int z = blockIdx.z;
    const float* in = z == 0 ? WQ : z == 1 ? WK : z == 2 ? WV : WO;
    f16* out = z < 3 ? wqkvt + (size_t)z * DEMB * DEMB : wot;
    const int c0 = blockIdx.x * 64, r0 = blockIdx.y * 64;
    const int tx = threadIdx.x & 63, ty = threadIdx.x >> 6;
    for (int rr = ty; rr < 64; rr += 4)
        tile[tx][rr] = (f16)in[(size_t)(r0 + rr) * DEMB + c0 + tx];
    __syncthreads();
    for (int cc = ty; cc < 64; cc += 4)
        out[(size_t)(c0 + cc) * DEMB + r0 + tx] = tile[cc][tx];
}

// ---------------------------------------------------------------------------
// 256x256-tile 8-phase GEMM (guide §5 template, T2+T3+T4+T5), BK=64,
// 8 waves (2Mx4N), per-phase = one 128x128 C-quadrant x K=64.
// A:[M][K] f16 row-major, BT:[N][K] f16 row-major.
// MODE 0: fused QKV. cols 0-2047 -> o0 (q16), 2048-4095 -> o1 (k16),
//         4096-6143 -> o2 = V stored TRANSPOSED [2048][4096]. biases b0/1/2.
// MODE 2: f32 out o0 [M][N] + bias b0 (final projection)
// MODE 3: f16 out o0 [M][N] * scale, triangular grid (scores)
// MODE 4: f16 out o0 [M][N], K limited to (bm+1)*256 (PV causal)
// ---------------------------------------------------------------------------
template <int MODE>
__global__ __launch_bounds__(512, 2)
void gemm256(const f16* __restrict__ A, const f16* __restrict__ BT,
             void* __restrict__ o0, void* __restrict__ o1, void* __restrict__ o2,
             const float* __restrict__ b0p, const float* __restrict__ b1p,
             const float* __restrict__ b2p, int M, int N, int K, float scale) {
    __shared__ f16 lds[65536];   // 128KB: [buf2][A/B][half2][128][64]

    int bm, bn;
    if (MODE == 3) {             // triangular decode: 136 live blocks
        const int bid = blockIdx.x;
        bm = (int)((sqrtf(8.f * bid + 1.f) - 1.f) * 0.5f);
        while ((bm + 1) * (bm + 2) / 2 <= bid) ++bm;
        while (bm * (bm + 1) / 2 > bid) --bm;
        bn = bid - bm * (bm + 1) / 2;
    } else { bn = blockIdx.x; bm = blockIdx.y; }

    const int m0 = bm * 256, n0 = bn * 256;
    const int NT = (MODE == 4) ? (bm + 1) * 4 : (K >> 6);   // K-tiles of 64
    const int NI = NT >> 1;                                 // 2 tiles/iter

    const int tid  = threadIdx.x;
    const int lane = tid & 63;
    const int wr   = (tid >> 6) >> 2;        // 0..1
    const int wc   = (tid >> 6) & 3;         // 0..3
    const int fr   = lane & 15;
    const int kb   = (lane >> 4) * 16;       // byte offset in K row (128B)

    const f16* Abase = A  + (size_t)m0 * K;
    const f16* Bbase = BT + (size_t)n0 * K;

#define STG(buf, isB, half, t) \
    stage_half(((isB) ? Bbase : Abase) + (size_t)((half) * 128) * K + (t) * 64, K, \
               lds + (buf) * 32768 + (isB) * 16384 + (half) * 8192, tid)

    f32x4 acc[8][4] = {};
    f16x8 af[8], bf0[4], bf1[4];

#define READ_A(Mh, buf) { \
    const f16* bb = lds + (buf) * 32768; \
    _Pragma("unroll") for (int m = 0; m < 4; ++m) \
    _Pragma("unroll") for (int ks = 0; ks < 2; ++ks) \
        af[m * 2 + ks] = ldsr(bb, ((Mh) * 128 + wr * 64 + m * 16 + fr) * 128 + ks * 64 + kb); }

#define READ_B(Nh, buf, dst) { \
    const f16* bb = lds + (buf) * 32768 + 16384; \
    _Pragma("unroll") for (int n = 0; n < 2; ++n) \
    _Pragma("unroll") for (int ks = 0; ks < 2; ++ks) \
        dst[n * 2 + ks] = ldsr(bb, ((Nh) * 128 + wc * 32 + n * 16 + fr) * 128 + ks * 64 + kb); }

#define MFMA_PH(Mh, Nh, bfx) { \
    __builtin_amdgcn_s_setprio(1); \
    _Pragma("unroll") for (int m = 0; m < 4; ++m) \
    _Pragma("unroll") for (int n = 0; n < 2; ++n) \
    _Pragma("unroll") for (int ks = 0; ks < 2; ++ks) \
        acc[(Mh) * 4 + m][(Nh) * 2 + n] = __builtin_amdgcn_mfma_f32_16x16x32_f16( \
            af[m * 2 + ks], bfx[n * 2 + ks], acc[(Mh) * 4 + m][(Nh) * 2 + n], 0, 0, 0); \
    __builtin_amdgcn_s_setprio(0); }

#define BAR   __builtin_amdgcn_s_barrier()
#define LGKM0 { asm volatile("s_waitcnt lgkmcnt(0)" ::: "memory"); \
                __builtin_amdgcn_sched_barrier(0); }
#define VM6   asm volatile("s_waitcnt vmcnt(6)" ::: "memory")
#define VM0   asm volatile("s_waitcnt vmcnt(0)" ::: "memory")

    // Prologue: tile0 (A0,B0,B1,A1) + tile1 (A0,B0,B1) = 7 half-tiles,
    // then vmcnt(6) -> tile0's 8 loads landed.
    STG(0, 0, 0, 0); STG(0, 1, 0, 0); STG(0, 1, 1, 0); STG(0, 0, 1, 0);
    STG(1, 0, 0, 1); STG(1, 1, 0, 1); STG(1, 1, 1, 1);
    VM6; BAR;

    for (int i = 0; i < NI; ++i) {
        const int t0 = 2 * i;
        const bool more = (i + 1 < NI);
        // ph1: quadrant (0,0) of tile t0 (buf0); stage buf1.A1 <- t0+1
        READ_A(0, 0); READ_B(0, 0, bf0);
        STG(1, 0, 1, t0 + 1);
        BAR; LGKM0; MFMA_PH(0, 0, bf0); BAR;
        // ph2: (0,1); stage buf0.A0 <- t0+2
        READ_B(1, 0, bf1);
        if (more) STG(0, 0, 0, t0 + 2);
        BAR; LGKM0; MFMA_PH(0, 1, bf1); BAR;
        // ph3: (1,0); stage buf0.B0 <- t0+2
        READ_A(1, 0);
        if (more) STG(0, 1, 0, t0 + 2);
        BAR; LGKM0; MFMA_PH(1, 0, bf0); BAR;
        // ph4: (1,1); stage buf0.B1 <- t0+2; counted vmcnt
        if (more) { STG(0, 1, 1, t0 + 2); VM6; } else { VM0; }
        BAR; LGKM0; MFMA_PH(1, 1, bf1); BAR;
        // ph5: quadrant (0,0) of tile t0+1 (buf1); stage buf0.A1 <- t0+2
        READ_A(0, 1); READ_B(0, 1, bf0);
        if (more) STG(0, 0, 1, t0 + 2);
        BAR; LGKM0; MFMA_PH(0, 0, bf0); BAR;
        // ph6: (0,1); stage buf1.A0 <- t0+3
        READ_B(1, 1, bf1);
        if (more) STG(1, 0, 0, t0 + 3);
        BAR; LGKM0; MFMA_PH(0, 1, bf1); BAR;
        // ph7: (1,0); stage buf1.B0 <- t0+3
        READ_A(1, 1);
        if (more) STG(1, 1, 0, t0 + 3);
        BAR; LGKM0; MFMA_PH(1, 0, bf0); BAR;
        // ph8: (1,1); stage buf1.B1 <- t0+3; counted vmcnt
        if (more) STG(1, 1, 1, t0 + 3);
        VM6;
        BAR; LGKM0; MFMA_PH(1, 1, bf1); BAR;
    }

    // Epilogue. C/D layout (verified): col = lane&15, row = (lane>>4)*4 + reg.
    const int rq = (lane >> 4) * 4;
#pragma unroll
    for (int mi = 0; mi < 8; ++mi) {
        const int row = m0 + (mi >> 2) * 128 + wr * 64 + (mi & 3) * 16 + rq;
#pragma unroll
        for (int ni = 0; ni < 4; ++ni) {
            const int col = n0 + (ni >> 1) * 128 + wc * 32 + (ni & 1) * 16 + fr;
            if (MODE == 0) {
                const int seg = col >> 11, c = col & 2047;
                const float bv = seg == 0 ? b0p[c] : seg == 1 ? b1p[c] : b2p[c];
                if (seg < 2) {
                    f16* o = seg ? (f16*)o1 : (f16*)o0;
#pragma unroll
                    for (int r = 0; r < 4; ++r)
                        o[(size_t)(row + r) * DEMB + c] = (f16)(acc[mi][ni][r] + bv);
                } else {
                    f16* o = (f16*)o2;          // V^T: [2048][4096]
#pragma unroll
                    for (int r = 0; r < 4; ++r)
                        o[(size_t)c * SEQ + row + r] = (f16)(acc[mi][ni][r] + bv);
                }
            } else if (MODE == 2) {
                float* o = (float*)o0;
                const float bv = b0p[col];
#pragma unroll
                for (int r = 0; r < 4; ++r)
                    o[(size_t)(row + r) * N + col] = acc[mi][ni][r] + bv;
            } else if (MODE == 3) {
                f16* o = (f16*)o0;
#pragma unroll
                for (int r = 0; r < 4; ++r)
                    o[(size_t)(row + r) * N + col] = (f16)(acc[mi][ni][r] * scale);
            } else {   // MODE 4
                f16* o = (f16*)o0;
#pragma unroll
                for (int r = 0; r < 4; ++r)
                    o[(size_t)(row + r) * N + col] = (f16)acc[mi][ni][r];
            }
        }
    }
#undef STG
#undef READ_A
#undef READ_B
#undef MFMA_PH
#undef BAR
#undef LGKM0
#undef VM6
#undef VM0
}

// ---------------------------------------------------------------------------
// Causal row softmax, in-place on S:[SEQ][SEQ] f16. Row staged in LDS once.
// Zeros [L, roundup(L,256)) so the 256-tile PV reads only defined data.
// ---------------------------------------------------------------------------
__global__ __launch_bounds__(256) void softmax_causal(f16* __restrict__ S) {
    __shared__ f16 srow[SEQ];
    __shared__ float red[8];
    const int i  = blockIdx.x;
    const int L  = i + 1;
    const int Lp = ((i >> 8) + 1) << 8;
    f16* row = S + (size_t)i * SEQ;
    const int t = threadIdx.x;

    float mx = -3.0e38f;
    for (int j0 = t * 8; j0 < Lp; j0 += 2048) {
        f16x8 v = *(const f16x8*)&row[j0];
        *(f16x8*)&srow[j0] = v;
#pragma unroll
        for (int u = 0; u < 8; ++u)
            if (j0 + u < L) mx = fmaxf(mx, (float)v[u]);
    }
#pragma unroll
    for (int o = 32; o > 0; o >>= 1) mx = fmaxf(mx, __shfl_xor(mx, o));
    if ((t & 63) == 0) red[t >> 6] = mx;
    __syncthreads();
    mx = fmaxf(fmaxf(red[0], red[1]), fmaxf(red[2], red[3]));

    float sm = 0.f;
    for (int j0 = t * 8; j0 < Lp; j0 += 2048) {
        f16x8 v = *(const f16x8*)&srow[j0];
#pragma unroll
        for (int u = 0; u < 8; ++u)
            if (j0 + u < L) sm += __expf((float)v[u] - mx);
    }
#pragma unroll
    for (int o = 32; o > 0; o >>= 1) sm += __shfl_xor(sm, o);
    if ((t & 63) == 0) red[4 + (t >> 6)] = sm;
    __syncthreads();
    const float inv = 1.f / (red[4] + red[5] + red[6] + red[7]);

    for (int j0 = t * 8; j0 < Lp; j0 += 2048) {
        f16x8 v = *(const f16x8*)&srow[j0];
        f16x8 wv;
#pragma unroll
        for (int u = 0; u < 8; ++u)
            wv[u] = (j0 + u < L) ? (f16)(__expf((float)v[u] - mx) * inv) : (f16)0.f;
        *(f16x8*)&row[j0] = wv;
    }
}

// ---------------------------------------------------------------------------
extern "C" void kernel_launch(void* const* d_in, const int* in_sizes, int n_in,
                              void* d_out, int out_size, void* d_ws, size_t ws_size,
                              hipStream_t stream) {
    const float* x  = (const float*)d_in[0];
    const float* WQ = (const float*)d_in[1];
    const float* WK = (const float*)d_in[2];
    const float* WV = (const float*)d_in[3];
    const float* WO = (const float*)d_in[4];
    const float* bQ = (const float*)d_in[5];
    const float* bK = (const float*)d_in[6];
    const float* bV = (const float*)d_in[7];
    const float* bO = (const float*)d_in[8];
    float* out = (float*)d_out;

    // workspace (~134 MB)
    char* w = (char*)d_ws;
    f16* x16   = (f16*)w; w += (size_t)SEQ * DEMB * 2;      // reused for attn out
    f16* q16   = (f16*)w; w += (size_t)SEQ * DEMB * 2;
    f16* k16   = (f16*)w; w += (size_t)SEQ * DEMB * 2;
    f16* vt16  = (f16*)w; w += (size_t)SEQ * DEMB * 2;      // V^T [2048][4096]
    f16* wqkvt = (f16*)w; w += (size_t)3 * DEMB * DEMB * 2; // [6144][2048]
    f16* wot   = (f16*)w; w += (size_t)DEMB * DEMB * 2;
    f16* sb    = (f16*)w; w += (size_t)SEQ * SEQ * 2;       // scores -> P
    f16* attn16 = x16;

    cvt_f16<<<(SEQ * DEMB) / 1024, 256, 0, stream>>>(x, x16, SEQ * DEMB);
    transpose_cvt4<<<dim3(DEMB / 64, DEMB / 64, 4), 256, 0, stream>>>(
        WQ, WK, WV, WO, wqkvt, wot);

    // fused QKV: [4096][2048] @ [6144][2048]^T -> q16/k16/vt16
    gemm256<0><<<dim3(3 * DEMB / 256, SEQ / 256), 512, 0, stream>>>(
        x16, wqkvt, q16, k16, vt16, bQ, bK, bV, SEQ, 3 * DEMB, DEMB, 1.f);

    // scores (triangular): q @ k^T * 1/sqrt(128)
    gemm256<3><<<136, 512, 0, stream>>>(
        q16, k16, sb, nullptr, nullptr, nullptr, nullptr, nullptr,
        SEQ, SEQ, DEMB, SCALE_QK);

    softmax_causal<<<SEQ, 256, 0, stream>>>(sb);

    // attn = P @ V  (BT = V^T), causal K limit
    gemm256<4><<<dim3(DEMB / 256, SEQ / 256), 512, 0, stream>>>(
        sb, vt16, attn16, nullptr, nullptr, nullptr, nullptr, nullptr,
        SEQ, DEMB, SEQ, 1.f);

    // out = attn @ W_O + b_O (f32)
    gemm256<2><<<dim3(DEMB / 256, SEQ / 256), 512, 0, stream>>>(
        attn16, wot, out, nullptr, nullptr, bO, nullptr, nullptr,
        SEQ, DEMB, DEMB, 1.f);
}

// Round 3
// 387.806 us; speedup vs baseline: 1.1919x; 1.0841x over previous
//
#include <hip/hip_runtime.h>
#include <hip/hip_fp16.h>

typedef _Float16 f16;
typedef _Float16 f16x8 __attribute__((ext_vector_type(8)));
typedef float    f32x4 __attribute__((ext_vector_type(4)));

#define SEQ      4096
#define DEMB     2048
#define SCALE_QK 0.08838834764831845f   // 1/sqrt(128)

#define GAS __attribute__((address_space(1)))
#define LAS __attribute__((address_space(3)))

// async global->LDS, 16B/lane. LDS dest = wave-uniform base + lane*16 (m104).
__device__ __forceinline__ void load_lds16(const f16* g, f16* l) {
    __builtin_amdgcn_global_load_lds((const GAS void*)g, (LAS void*)l, 16, 0, 0);
}

// Swizzled LDS read: 16B slot (bits 4-6) ^= row&7 (bits 7-9). Uniform
// 8-lanes-per-slot for the wave's b128 pattern -> all 32 banks busy (the
// b128 floor). Involution; row bits unchanged.
__device__ __forceinline__ f16x8 ldsr(const f16* base, int byteoff) {
    byteoff ^= (byteoff >> 3) & 0x70;
    return *(const f16x8*)((const char*)base + byteoff);
}

// Stage one half-tile [128 rows][64 f16] (16KB) into LDS (linear dest,
// inverse-swizzled per-lane SOURCE per rule #21). 512 threads, 2 issues.
__device__ __forceinline__ void stage_half(const f16* __restrict__ src, int ldk,
                                           f16* ldsdst, int tid) {
#pragma unroll
    for (int s = 0; s < 2; ++s) {
        const int o   = s * 8192 + tid * 16;           // linear byte off in half
        const int osw = o ^ ((o >> 3) & 0x70);         // pre-swizzled source
        load_lds16(src + (size_t)(osw >> 7) * ldk + ((osw & 127) >> 1),
                   ldsdst + (s * 8192 + (tid >> 6) * 1024) / 2);
    }
}

// ---------------------------------------------------------------------------
// fp32 -> fp16 convert (x)
// ---------------------------------------------------------------------------
__global__ __launch_bounds__(256) void cvt_f16(const float* __restrict__ in,
                                               f16* __restrict__ out, int n) {
    int i = (blockIdx.x * 256 + threadIdx.x) * 4;
    if (i >= n) return;
    float4 v = *(const float4*)&in[i];
    f16 o0 = (f16)v.x, o1 = (f16)v.y, o2 = (f16)v.z, o3 = (f16)v.w;
    f16* p = &out[i];
    p[0] = o0; p[1] = o1; p[2] = o2; p[3] = o3;
}

// ---------------------------------------------------------------------------
// All four weights: fp32 [2048][2048] -> fp16 transposed. z selects matrix.
// z<3 -> wqkvt (concat W_Q^T, W_K^T, W_V^T), z==3 -> wot.
// ---------------------------------------------------------------------------
__global__ __launch_bounds__(256) void transpose_cvt4(
        const float* __restrict__ WQ, const float* __restrict__ WK,
        const float* __restrict__ WV, const float* __restrict__ WO,
        f16* __restrict__ wqkvt, f16* __restrict__ wot) {
    __shared__ f16 tile[64][72];
    const int z = blockIdx.z;
    const float* in = z == 0 ? WQ : z == 1 ? WK : z == 2 ? WV : WO;
    f16* out = z < 3 ? wqkvt + (size_t)z * DEMB * DEMB : wot;
    const int c0 = blockIdx.x * 64, r0 = blockIdx.y * 64;
    const int tx = threadIdx.x & 63, ty = threadIdx.x >> 6;
    for (int rr = ty; rr < 64; rr += 4)
        tile[tx][rr] = (f16)in[(size_t)(r0 + rr) * DEMB + c0 + tx];
    __syncthreads();
    for (int cc = ty; cc < 64; cc += 4)
        out[(size_t)(c0 + cc) * DEMB + r0 + tx] = tile[cc][tx];
}

// ---------------------------------------------------------------------------
// 256x256-tile 8-phase GEMM (guide §5 template, T2+T3+T4+T5), BK=64,
// 8 waves (2Mx4N), per-phase = one 128x128 C-quadrant x K=64.
// A:[M][K] f16 row-major, BT:[N][K] f16 row-major.
// MODE 0: fused QKV. cols 0-2047 -> o0 (q16), 2048-4095 -> o1 (k16),
//         4096-6143 -> o2 = V stored TRANSPOSED [2048][4096]. biases b0/1/2.
// MODE 2: f32 out o0 [M][N] + bias b0 (final projection)
// MODE 3: f16 out o0 [M][N] * scale, triangular grid (scores)
// MODE 4: f16 out o0 [M][N], K limited to (bm+1)*256 (PV causal)
// ---------------------------------------------------------------------------
template <int MODE>
__global__ __launch_bounds__(512, 2)
void gemm256(const f16* __restrict__ A, const f16* __restrict__ BT,
             void* __restrict__ o0, void* __restrict__ o1, void* __restrict__ o2,
             const float* __restrict__ b0p, const float* __restrict__ b1p,
             const float* __restrict__ b2p, int M, int N, int K, float scale) {
    __shared__ f16 lds[65536];   // 128KB: [buf2][A/B][half2][128][64]

    int bm, bn;
    if (MODE == 3) {             // triangular decode: 136 live blocks
        const int bid = blockIdx.x;
        bm = (int)((sqrtf(8.f * bid + 1.f) - 1.f) * 0.5f);
        while ((bm + 1) * (bm + 2) / 2 <= bid) ++bm;
        while (bm * (bm + 1) / 2 > bid) --bm;
        bn = bid - bm * (bm + 1) / 2;
    } else { bn = blockIdx.x; bm = blockIdx.y; }

    const int m0 = bm * 256, n0 = bn * 256;
    const int NT = (MODE == 4) ? (bm + 1) * 4 : (K >> 6);   // K-tiles of 64
    const int NI = NT >> 1;                                 // 2 tiles/iter

    const int tid  = threadIdx.x;
    const int lane = tid & 63;
    const int wr   = (tid >> 6) >> 2;        // 0..1
    const int wc   = (tid >> 6) & 3;         // 0..3
    const int fr   = lane & 15;
    const int kb   = (lane >> 4) * 16;       // byte offset in K row (128B)

    const f16* Abase = A  + (size_t)m0 * K;
    const f16* Bbase = BT + (size_t)n0 * K;

#define STG(buf, isB, half, t) \
    stage_half(((isB) ? Bbase : Abase) + (size_t)((half) * 128) * K + (t) * 64, K, \
               lds + (buf) * 32768 + (isB) * 16384 + (half) * 8192, tid)

    f32x4 acc[8][4] = {};
    f16x8 af[8], bf0[4], bf1[4];

#define READ_A(Mh, buf) { \
    const f16* bb = lds + (buf) * 32768; \
    _Pragma("unroll") for (int m = 0; m < 4; ++m) \
    _Pragma("unroll") for (int ks = 0; ks < 2; ++ks) \
        af[m * 2 + ks] = ldsr(bb, ((Mh) * 128 + wr * 64 + m * 16 + fr) * 128 + ks * 64 + kb); }

#define READ_B(Nh, buf, dst) { \
    const f16* bb = lds + (buf) * 32768 + 16384; \
    _Pragma("unroll") for (int n = 0; n < 2; ++n) \
    _Pragma("unroll") for (int ks = 0; ks < 2; ++ks) \
        dst[n * 2 + ks] = ldsr(bb, ((Nh) * 128 + wc * 32 + n * 16 + fr) * 128 + ks * 64 + kb); }

#define MFMA_PH(Mh, Nh, bfx) { \
    __builtin_amdgcn_s_setprio(1); \
    _Pragma("unroll") for (int m = 0; m < 4; ++m) \
    _Pragma("unroll") for (int n = 0; n < 2; ++n) \
    _Pragma("unroll") for (int ks = 0; ks < 2; ++ks) \
        acc[(Mh) * 4 + m][(Nh) * 2 + n] = __builtin_amdgcn_mfma_f32_16x16x32_f16( \
            af[m * 2 + ks], bfx[n * 2 + ks], acc[(Mh) * 4 + m][(Nh) * 2 + n], 0, 0, 0); \
    __builtin_amdgcn_s_setprio(0); }

#define BAR   __builtin_amdgcn_s_barrier()
#define LGKM0 { asm volatile("s_waitcnt lgkmcnt(0)" ::: "memory"); \
                __builtin_amdgcn_sched_barrier(0); }
#define VM6   asm volatile("s_waitcnt vmcnt(6)" ::: "memory")
#define VM0   asm volatile("s_waitcnt vmcnt(0)" ::: "memory")

    // Prologue: tile0 (A0,B0,B1,A1) + tile1 (A0,B0,B1) = 7 half-tiles,
    // then vmcnt(6) -> tile0's 8 loads landed.
    STG(0, 0, 0, 0); STG(0, 1, 0, 0); STG(0, 1, 1, 0); STG(0, 0, 1, 0);
    STG(1, 0, 0, 1); STG(1, 1, 0, 1); STG(1, 1, 1, 1);
    VM6; BAR;

    for (int i = 0; i < NI; ++i) {
        const int t0 = 2 * i;
        const bool more = (i + 1 < NI);
        // ph1: quadrant (0,0) of tile t0 (buf0); stage buf1.A1 <- t0+1
        READ_A(0, 0); READ_B(0, 0, bf0);
        STG(1, 0, 1, t0 + 1);
        BAR; LGKM0; MFMA_PH(0, 0, bf0); BAR;
        // ph2: (0,1); stage buf0.A0 <- t0+2
        READ_B(1, 0, bf1);
        if (more) STG(0, 0, 0, t0 + 2);
        BAR; LGKM0; MFMA_PH(0, 1, bf1); BAR;
        // ph3: (1,0); stage buf0.B0 <- t0+2
        READ_A(1, 0);
        if (more) STG(0, 1, 0, t0 + 2);
        BAR; LGKM0; MFMA_PH(1, 0, bf0); BAR;
        // ph4: (1,1); stage buf0.B1 <- t0+2; counted vmcnt
        if (more) { STG(0, 1, 1, t0 + 2); VM6; } else { VM0; }
        BAR; LGKM0; MFMA_PH(1, 1, bf1); BAR;
        // ph5: quadrant (0,0) of tile t0+1 (buf1); stage buf0.A1 <- t0+2
        READ_A(0, 1); READ_B(0, 1, bf0);
        if (more) STG(0, 0, 1, t0 + 2);
        BAR; LGKM0; MFMA_PH(0, 0, bf0); BAR;
        // ph6: (0,1); stage buf1.A0 <- t0+3
        READ_B(1, 1, bf1);
        if (more) STG(1, 0, 0, t0 + 3);
        BAR; LGKM0; MFMA_PH(0, 1, bf1); BAR;
        // ph7: (1,0); stage buf1.B0 <- t0+3
        READ_A(1, 1);
        if (more) STG(1, 1, 0, t0 + 3);
        BAR; LGKM0; MFMA_PH(1, 0, bf0); BAR;
        // ph8: (1,1); stage buf1.B1 <- t0+3; counted vmcnt
        if (more) STG(1, 1, 1, t0 + 3);
        VM6;
        BAR; LGKM0; MFMA_PH(1, 1, bf1); BAR;
    }

    // Epilogue. C/D layout (verified): col = lane&15, row = (lane>>4)*4 + reg.
    const int rq = (lane >> 4) * 4;
#pragma unroll
    for (int mi = 0; mi < 8; ++mi) {
        const int row = m0 + (mi >> 2) * 128 + wr * 64 + (mi & 3) * 16 + rq;
#pragma unroll
        for (int ni = 0; ni < 4; ++ni) {
            const int col = n0 + (ni >> 1) * 128 + wc * 32 + (ni & 1) * 16 + fr;
            if (MODE == 0) {
                const int seg = col >> 11, c = col & 2047;
                const float bv = seg == 0 ? b0p[c] : seg == 1 ? b1p[c] : b2p[c];
                if (seg < 2) {
                    f16* o = seg ? (f16*)o1 : (f16*)o0;
#pragma unroll
                    for (int r = 0; r < 4; ++r)
                        o[(size_t)(row + r) * DEMB + c] = (f16)(acc[mi][ni][r] + bv);
                } else {
                    f16* o = (f16*)o2;          // V^T: [2048][4096]
#pragma unroll
                    for (int r = 0; r < 4; ++r)
                        o[(size_t)c * SEQ + row + r] = (f16)(acc[mi][ni][r] + bv);
                }
            } else if (MODE == 2) {
                float* o = (float*)o0;
                const float bv = b0p[col];
#pragma unroll
                for (int r = 0; r < 4; ++r)
                    o[(size_t)(row + r) * N + col] = acc[mi][ni][r] + bv;
            } else if (MODE == 3) {
                f16* o = (f16*)o0;
#pragma unroll
                for (int r = 0; r < 4; ++r)
                    o[(size_t)(row + r) * N + col] = (f16)(acc[mi][ni][r] * scale);
            } else {   // MODE 4
                f16* o = (f16*)o0;
#pragma unroll
                for (int r = 0; r < 4; ++r)
                    o[(size_t)(row + r) * N + col] = (f16)acc[mi][ni][r];
            }
        }
    }
#undef STG
#undef READ_A
#undef READ_B
#undef MFMA_PH
#undef BAR
#undef LGKM0
#undef VM6
#undef VM0
}

// ---------------------------------------------------------------------------
// Causal row softmax, in-place on S:[SEQ][SEQ] f16. Row staged in LDS once.
// Zeros [L, roundup(L,256)) so the 256-tile PV reads only defined data.
// ---------------------------------------------------------------------------
__global__ __launch_bounds__(256) void softmax_causal(f16* __restrict__ S) {
    __shared__ f16 srow[SEQ];
    __shared__ float red[8];
    const int i  = blockIdx.x;
    const int L  = i + 1;
    const int Lp = ((i >> 8) + 1) << 8;
    f16* row = S + (size_t)i * SEQ;
    const int t = threadIdx.x;

    float mx = -3.0e38f;
    for (int j0 = t * 8; j0 < Lp; j0 += 2048) {
        f16x8 v = *(const f16x8*)&row[j0];
        *(f16x8*)&srow[j0] = v;
#pragma unroll
        for (int u = 0; u < 8; ++u)
            if (j0 + u < L) mx = fmaxf(mx, (float)v[u]);
    }
#pragma unroll
    for (int o = 32; o > 0; o >>= 1) mx = fmaxf(mx, __shfl_xor(mx, o));
    if ((t & 63) == 0) red[t >> 6] = mx;
    __syncthreads();
    mx = fmaxf(fmaxf(red[0], red[1]), fmaxf(red[2], red[3]));

    float sm = 0.f;
    for (int j0 = t * 8; j0 < Lp; j0 += 2048) {
        f16x8 v = *(const f16x8*)&srow[j0];
#pragma unroll
        for (int u = 0; u < 8; ++u)
            if (j0 + u < L) sm += __expf((float)v[u] - mx);
    }
#pragma unroll
    for (int o = 32; o > 0; o >>= 1) sm += __shfl_xor(sm, o);
    if ((t & 63) == 0) red[4 + (t >> 6)] = sm;
    __syncthreads();
    const float inv = 1.f / (red[4] + red[5] + red[6] + red[7]);

    for (int j0 = t * 8; j0 < Lp; j0 += 2048) {
        f16x8 v = *(const f16x8*)&srow[j0];
        f16x8 wv;
#pragma unroll
        for (int u = 0; u < 8; ++u)
            wv[u] = (j0 + u < L) ? (f16)(__expf((float)v[u] - mx) * inv) : (f16)0.f;
        *(f16x8*)&row[j0] = wv;
    }
}

// ---------------------------------------------------------------------------
extern "C" void kernel_launch(void* const* d_in, const int* in_sizes, int n_in,
                              void* d_out, int out_size, void* d_ws, size_t ws_size,
                              hipStream_t stream) {
    const float* x  = (const float*)d_in[0];
    const float* WQ = (const float*)d_in[1];
    const float* WK = (const float*)d_in[2];
    const float* WV = (const float*)d_in[3];
    const float* WO = (const float*)d_in[4];
    const float* bQ = (const float*)d_in[5];
    const float* bK = (const float*)d_in[6];
    const float* bV = (const float*)d_in[7];
    const float* bO = (const float*)d_in[8];
    float* out = (float*)d_out;

    // workspace (~134 MB)
    char* w = (char*)d_ws;
    f16* x16   = (f16*)w; w += (size_t)SEQ * DEMB * 2;      // reused for attn out
    f16* q16   = (f16*)w; w += (size_t)SEQ * DEMB * 2;
    f16* k16   = (f16*)w; w += (size_t)SEQ * DEMB * 2;
    f16* vt16  = (f16*)w; w += (size_t)SEQ * DEMB * 2;      // V^T [2048][4096]
    f16* wqkvt = (f16*)w; w += (size_t)3 * DEMB * DEMB * 2; // [6144][2048]
    f16* wot   = (f16*)w; w += (size_t)DEMB * DEMB * 2;
    f16* sb    = (f16*)w; w += (size_t)SEQ * SEQ * 2;       // scores -> P
    f16* attn16 = x16;

    cvt_f16<<<(SEQ * DEMB) / 1024, 256, 0, stream>>>(x, x16, SEQ * DEMB);
    transpose_cvt4<<<dim3(DEMB / 64, DEMB / 64, 4), 256, 0, stream>>>(
        WQ, WK, WV, WO, wqkvt, wot);

    // fused QKV: [4096][2048] @ [6144][2048]^T -> q16/k16/vt16
    gemm256<0><<<dim3(3 * DEMB / 256, SEQ / 256), 512, 0, stream>>>(
        x16, wqkvt, q16, k16, vt16, bQ, bK, bV, SEQ, 3 * DEMB, DEMB, 1.f);

    // scores (triangular): q @ k^T * 1/sqrt(128)
    gemm256<3><<<136, 512, 0, stream>>>(
        q16, k16, sb, nullptr, nullptr, nullptr, nullptr, nullptr,
        SEQ, SEQ, DEMB, SCALE_QK);

    softmax_causal<<<SEQ, 256, 0, stream>>>(sb);

    // attn = P @ V  (BT = V^T), causal K limit
    gemm256<4><<<dim3(DEMB / 256, SEQ / 256), 512, 0, stream>>>(
        sb, vt16, attn16, nullptr, nullptr, nullptr, nullptr, nullptr,
        SEQ, DEMB, SEQ, 1.f);

    // out = attn @ W_O + b_O (f32)
    gemm256<2><<<dim3(DEMB / 256, SEQ / 256), 512, 0, stream>>>(
        attn16, wot, out, nullptr, nullptr, bO, nullptr, nullptr,
        SEQ, DEMB, DEMB, 1.f);
}

// Round 5
// 347.153 us; speedup vs baseline: 1.3315x; 1.1171x over previous
//
#include <hip/hip_runtime.h>
#include <hip/hip_fp16.h>

typedef _Float16 f16;
typedef _Float16 f16x8 __attribute__((ext_vector_type(8)));
typedef _Float16 f16x4 __attribute__((ext_vector_type(4)));
typedef float    f32x4 __attribute__((ext_vector_type(4)));

#define SEQ      4096
#define DEMB     2048
#define SCALE_QK 0.08838834764831845f   // 1/sqrt(128)

#define GAS __attribute__((address_space(1)))
#define LAS __attribute__((address_space(3)))

__device__ __forceinline__ void load_lds16(const f16* g, f16* l) {
    __builtin_amdgcn_global_load_lds((const GAS void*)g, (LAS void*)l, 16, 0, 0);
}

// Swizzled LDS read: 16B slot (bits 4-6) ^= row&7 (bits 7-9). Verified R3:
// bank conflicts -> 0.
__device__ __forceinline__ f16x8 ldsr(const f16* base, int byteoff) {
    byteoff ^= (byteoff >> 3) & 0x70;
    return *(const f16x8*)((const char*)base + byteoff);
}

// Stage one half-tile [128 rows][64 f16] into LDS: linear dest,
// inverse-swizzled per-lane source (rule #21). 512 threads, 2 issues.
__device__ __forceinline__ void stage_half(const f16* __restrict__ src, int ldk,
                                           f16* ldsdst, int tid) {
#pragma unroll
    for (int s = 0; s < 2; ++s) {
        const int o   = s * 8192 + tid * 16;
        const int osw = o ^ ((o >> 3) & 0x70);
        load_lds16(src + (size_t)(osw >> 7) * ldk + ((osw & 127) >> 1),
                   ldsdst + (s * 8192 + (tid >> 6) * 1024) / 2);
    }
}

// ---------------------------------------------------------------------------
// 256x256-tile 8-phase GEMM core (T2+T3+T4+T5), BK=64, 8 waves (2Mx4N).
// Relaxed waits: barriers are compiler memory fences; ds_read->MFMA waits are
// compiler-inserted (counted, fine-grained). vmcnt ledger unchanged from R2/R3.
// MODE 0: f16 out[row*ldo+col] = acc + bias[col]
// MODE 1: f16 out[col*ldo+row] = acc              (transposed store, no bias)
// MODE 2: f32 atomicAdd(out[row*ldo+col], acc + (bias?bias[col]:0))
// MODE 3: f16 out[row*ldo+col] = acc * scale
// ---------------------------------------------------------------------------
template <int MODE>
__device__ __forceinline__ void gemm_core(
        const f16* __restrict__ A, int lda, const f16* __restrict__ BT, int ldb,
        void* __restrict__ outp, int ldo, const float* __restrict__ bias,
        int bm, int bn, int NTc, int kt0, float scale, f16* lds) {
    const int m0 = bm * 256, n0 = bn * 256;
    const int NI = NTc >> 1;

    const int tid  = threadIdx.x;
    const int lane = tid & 63;
    const int wr   = (tid >> 6) >> 2;
    const int wc   = (tid >> 6) & 3;
    const int fr   = lane & 15;
    const int kb   = (lane >> 4) * 16;

    const f16* Abase = A + (size_t)m0 * lda + kt0 * 64;
    const f16* Bbase = BT + (size_t)n0 * ldb + kt0 * 64;

#define STG(buf, isB, half, t) \
    stage_half((isB) ? (Bbase + (size_t)((half) * 128) * ldb + (t) * 64) \
                     : (Abase + (size_t)((half) * 128) * lda + (t) * 64), \
               (isB) ? ldb : lda, \
               lds + (buf) * 32768 + (isB) * 16384 + (half) * 8192, tid)

    f32x4 acc[8][4] = {};
    f16x8 af[8], bf0[4], bf1[4];

#define READ_A(Mh, buf) { \
    const f16* bb = lds + (buf) * 32768; \
    _Pragma("unroll") for (int m = 0; m < 4; ++m) \
    _Pragma("unroll") for (int ks = 0; ks < 2; ++ks) \
        af[m * 2 + ks] = ldsr(bb, ((Mh) * 128 + wr * 64 + m * 16 + fr) * 128 + ks * 64 + kb); }

#define READ_B(Nh, buf, dst) { \
    const f16* bb = lds + (buf) * 32768 + 16384; \
    _Pragma("unroll") for (int n = 0; n < 2; ++n) \
    _Pragma("unroll") for (int ks = 0; ks < 2; ++ks) \
        dst[n * 2 + ks] = ldsr(bb, ((Nh) * 128 + wc * 32 + n * 16 + fr) * 128 + ks * 64 + kb); }

#define MFMA_PH(Mh, Nh, bfx) { \
    __builtin_amdgcn_s_setprio(1); \
    _Pragma("unroll") for (int m = 0; m < 4; ++m) \
    _Pragma("unroll") for (int n = 0; n < 2; ++n) \
    _Pragma("unroll") for (int ks = 0; ks < 2; ++ks) \
        acc[(Mh) * 4 + m][(Nh) * 2 + n] = __builtin_amdgcn_mfma_f32_16x16x32_f16( \
            af[m * 2 + ks], bfx[n * 2 + ks], acc[(Mh) * 4 + m][(Nh) * 2 + n], 0, 0, 0); \
    __builtin_amdgcn_s_setprio(0); }

#define BAR   asm volatile("s_barrier" ::: "memory")
#define VM6   asm volatile("s_waitcnt vmcnt(6)" ::: "memory")
#define VM0   asm volatile("s_waitcnt vmcnt(0)" ::: "memory")

    STG(0, 0, 0, 0); STG(0, 1, 0, 0); STG(0, 1, 1, 0); STG(0, 0, 1, 0);
    STG(1, 0, 0, 1); STG(1, 1, 0, 1); STG(1, 1, 1, 1);
    VM6; BAR;

    for (int i = 0; i < NI; ++i) {
        const int t0 = 2 * i;
        const bool more = (i + 1 < NI);
        READ_A(0, 0); READ_B(0, 0, bf0);
        STG(1, 0, 1, t0 + 1);
        BAR; MFMA_PH(0, 0, bf0); BAR;
        READ_B(1, 0, bf1);
        if (more) STG(0, 0, 0, t0 + 2);
        BAR; MFMA_PH(0, 1, bf1); BAR;
        READ_A(1, 0);
        if (more) STG(0, 1, 0, t0 + 2);
        BAR; MFMA_PH(1, 0, bf0); BAR;
        if (more) { STG(0, 1, 1, t0 + 2); VM6; } else { VM0; }
        BAR; MFMA_PH(1, 1, bf1); BAR;
        READ_A(0, 1); READ_B(0, 1, bf0);
        if (more) STG(0, 0, 1, t0 + 2);
        BAR; MFMA_PH(0, 0, bf0); BAR;
        READ_B(1, 1, bf1);
        if (more) STG(1, 0, 0, t0 + 3);
        BAR; MFMA_PH(0, 1, bf1); BAR;
        READ_A(1, 1);
        if (more) STG(1, 1, 0, t0 + 3);
        BAR; MFMA_PH(1, 0, bf0); BAR;
        if (more) STG(1, 1, 1, t0 + 3);
        VM6;
        BAR; MFMA_PH(1, 1, bf1); BAR;
    }

    const int rq = (lane >> 4) * 4;
#pragma unroll
    for (int mi = 0; mi < 8; ++mi) {
        const int row = m0 + (mi >> 2) * 128 + wr * 64 + (mi & 3) * 16 + rq;
#pragma unroll
        for (int ni = 0; ni < 4; ++ni) {
            const int col = n0 + (ni >> 1) * 128 + wc * 32 + (ni & 1) * 16 + fr;
            if (MODE == 0) {
                f16* o = (f16*)outp;
                const float bv = bias[col];
#pragma unroll
                for (int r = 0; r < 4; ++r)
                    o[(size_t)(row + r) * ldo + col] = (f16)(acc[mi][ni][r] + bv);
            } else if (MODE == 1) {
                f16* o = (f16*)outp;
                f16x4 v;
#pragma unroll
                for (int r = 0; r < 4; ++r) v[r] = (f16)acc[mi][ni][r];
                *(f16x4*)&o[(size_t)col * ldo + row] = v;
            } else if (MODE == 2) {
                float* o = (float*)outp;
                const float bv = bias ? bias[col] : 0.f;
#pragma unroll
                for (int r = 0; r < 4; ++r)
                    atomicAdd(&o[(size_t)(row + r) * ldo + col], acc[mi][ni][r] + bv);
            } else {
                f16* o = (f16*)outp;
#pragma unroll
                for (int r = 0; r < 4; ++r)
                    o[(size_t)(row + r) * ldo + col] = (f16)(acc[mi][ni][r] * scale);
            }
        }
    }
#undef STG
#undef READ_A
#undef READ_B
#undef MFMA_PH
#undef BAR
#undef VM6
#undef VM0
}

// ---------------------------------------------------------------------------
__global__ __launch_bounds__(256) void cvt_f16(const float* __restrict__ in,
                                               f16* __restrict__ out, int n) {
    int i = (blockIdx.x * 256 + threadIdx.x) * 4;
    if (i >= n) return;
    float4 v = *(const float4*)&in[i];
    f16x4 o; o[0] = (f16)v.x; o[1] = (f16)v.y; o[2] = (f16)v.z; o[3] = (f16)v.w;
    *(f16x4*)&out[i] = o;
}

__global__ __launch_bounds__(256) void transpose_cvt4(
        const float* __restrict__ WQ, const float* __restrict__ WK,
        const float* __restrict__ WV, const float* __restrict__ WO,
        f16* __restrict__ wqkvt, f16* __restrict__ wot) {
    __shared__ f16 tile[64][72];
    const int z = blockIdx.z;
    const float* in = z == 0 ? WQ : z == 1 ? WK : z == 2 ? WV : WO;
    f16* out = z < 3 ? wqkvt + (size_t)z * DEMB * DEMB : wot;
    const int c0 = blockIdx.x * 64, r0 = blockIdx.y * 64;
    const int tx = threadIdx.x & 63, ty = threadIdx.x >> 6;
    for (int rr = ty; rr < 64; rr += 4)
        tile[tx][rr] = (f16)in[(size_t)(r0 + rr) * DEMB + c0 + tx];
    __syncthreads();
    for (int cc = ty; cc < 64; cc += 4)
        out[(size_t)(c0 + cc) * DEMB + r0 + tx] = tile[cc][tx];
}

// QKV: x16 @ wqkvt^T -> qkv16 [4096][6144] (+concat bias)
__global__ __launch_bounds__(512, 2)
void k_qkv(const f16* __restrict__ x16, const f16* __restrict__ wqkvt,
           f16* __restrict__ qkv16, const float* __restrict__ bqkv) {
    __shared__ f16 lds[65536];
    gemm_core<0>(x16, DEMB, wqkvt, DEMB, qkv16, 3 * DEMB, bqkv,
                 blockIdx.y, blockIdx.x, 32, 0, 1.f, lds);
}

// scores (triangular): Q @ K^T * scale -> sb [4096][4096] f16
__global__ __launch_bounds__(512, 2)
void k_scores(const f16* __restrict__ qkv16, f16* __restrict__ sb) {
    __shared__ f16 lds[65536];
    const int bid = blockIdx.x;
    int bm = (int)((sqrtf(8.f * bid + 1.f) - 1.f) * 0.5f);
    while ((bm + 1) * (bm + 2) / 2 <= bid) ++bm;
    while (bm * (bm + 1) / 2 > bid) --bm;
    const int bn = bid - bm * (bm + 1) / 2;
    gemm_core<3>(qkv16, 3 * DEMB, qkv16 + DEMB, 3 * DEMB, sb, SEQ, nullptr,
                 bm, bn, 32, 0, SCALE_QK, lds);
}

// Fused: blocks 0-127 compute VW^T = (V @ W_O)^T -> vwT [2048][4096];
// blocks 128+ run causal softmax (2 rows each) on sb in-place.
// Softmax pads rows with zeros to 256-boundary for the PVW tile loop.
__global__ __launch_bounds__(512, 2)
void k_vw_softmax(const f16* __restrict__ qkv16, const f16* __restrict__ wot,
                  f16* __restrict__ vwT, f16* __restrict__ sb) {
    __shared__ f16 lds[65536];
    const int bid = blockIdx.x;
    if (bid < 128) {
        gemm_core<1>(qkv16 + 2 * DEMB, 3 * DEMB, wot, DEMB, vwT, SEQ, nullptr,
                     bid >> 3, bid & 7, 32, 0, 1.f, lds);
        return;
    }
    // softmax: half-blocks of 256 threads, one row each
    f16* srow = lds + (size_t)(threadIdx.x >> 8) * SEQ;          // [2][4096]
    float* red = (float*)(lds + 2 * SEQ);                        // [2][8]
    const int half = threadIdx.x >> 8;
    const int tt   = threadIdx.x & 255;
    const int i    = 2 * (bid - 128) + half;
    const int L    = i + 1;
    const int Lp   = ((i >> 8) + 1) << 8;
    f16* row = sb + (size_t)i * SEQ;

    float mx = -3.0e38f;
    for (int j0 = tt * 8; j0 < Lp; j0 += 2048) {
        f16x8 v = *(const f16x8*)&row[j0];
        *(f16x8*)&srow[j0] = v;
#pragma unroll
        for (int u = 0; u < 8; ++u)
            if (j0 + u < L) mx = fmaxf(mx, (float)v[u]);
    }
#pragma unroll
    for (int o = 32; o > 0; o >>= 1) mx = fmaxf(mx, __shfl_xor(mx, o));
    if ((tt & 63) == 0) red[half * 8 + (tt >> 6)] = mx;
    __syncthreads();
    mx = fmaxf(fmaxf(red[half * 8 + 0], red[half * 8 + 1]),
               fmaxf(red[half * 8 + 2], red[half * 8 + 3]));

    float sm = 0.f;
    for (int j0 = tt * 8; j0 < Lp; j0 += 2048) {
        f16x8 v = *(const f16x8*)&srow[j0];
#pragma unroll
        for (int u = 0; u < 8; ++u)
            if (j0 + u < L) sm += __expf((float)v[u] - mx);
    }
#pragma unroll
    for (int o = 32; o > 0; o >>= 1) sm += __shfl_xor(sm, o);
    if ((tt & 63) == 0) red[half * 8 + 4 + (tt >> 6)] = sm;
    __syncthreads();
    const float inv = 1.f / (red[half * 8 + 4] + red[half * 8 + 5] +
                             red[half * 8 + 6] + red[half * 8 + 7]);

    for (int j0 = tt * 8; j0 < Lp; j0 += 2048) {
        f16x8 v = *(const f16x8*)&srow[j0];
        f16x8 wv;
#pragma unroll
        for (int u = 0; u < 8; ++u)
            wv[u] = (j0 + u < L) ? (f16)(__expf((float)v[u] - mx) * inv) : (f16)0.f;
        *(f16x8*)&row[j0] = wv;
    }
}

// PVW: out = P @ VW + b_O, f32, causal K-limit, split-K (z in {0,1}),
// atomicAdd into memset-zero d_out (2 commutative contributions -> determ.).
__global__ __launch_bounds__(512, 2)
void k_pvw(const f16* __restrict__ sb, const f16* __restrict__ vwT,
           float* __restrict__ out, const float* __restrict__ bO) {
    __shared__ f16 lds[65536];
    const int bm = blockIdx.y, bn = blockIdx.x, z = blockIdx.z;
    const int NT = (bm + 1) * 4;        // K-tiles of 64 in causal range
    const int half = NT >> 1;           // even (NT = 4*(bm+1))
    gemm_core<2>(sb, SEQ, vwT, SEQ, out, DEMB, z == 0 ? bO : nullptr,
                 bm, bn, half, z * half, 1.f, lds);
}

// ---------------------------------------------------------------------------
extern "C" void kernel_launch(void* const* d_in, const int* in_sizes, int n_in,
                              void* d_out, int out_size, void* d_ws, size_t ws_size,
                              hipStream_t stream) {
    const float* x  = (const float*)d_in[0];
    const float* WQ = (const float*)d_in[1];
    const float* WK = (const float*)d_in[2];
    const float* WV = (const float*)d_in[3];
    const float* WO = (const float*)d_in[4];
    const float* bQ = (const float*)d_in[5];
    const float* bK = (const float*)d_in[6];
    const float* bV = (const float*)d_in[7];
    const float* bO = (const float*)d_in[8];
    float* out = (float*)d_out;

    // workspace layout (~118 MB); sb aliases {x16, wqkvt} (dead after QKV)
    char* w = (char*)d_ws;
    f16* qkv16 = (f16*)w; w += (size_t)SEQ * 3 * DEMB * 2;    // 50.3 MB
    f16* vwT   = (f16*)w; w += (size_t)DEMB * SEQ * 2;        // 16.8 MB
    f16* wot   = (f16*)w; w += (size_t)DEMB * DEMB * 2;       //  8.4 MB
    float* bqkv = (float*)w; w += 3 * DEMB * 4 + 8192;        // 24.6 KB (+pad)
    char* R = w;
    f16* x16   = (f16*)R;
    f16* wqkvt = (f16*)(R + (size_t)SEQ * DEMB * 2);
    f16* sb    = (f16*)R;                                     // 33.5 MB alias

    cvt_f16<<<(SEQ * DEMB) / 1024, 256, 0, stream>>>(x, x16, SEQ * DEMB);
    transpose_cvt4<<<dim3(DEMB / 64, DEMB / 64, 4), 256, 0, stream>>>(
        WQ, WK, WV, WO, wqkvt, wot);
    hipMemcpyAsync(bqkv, bQ, DEMB * 4, hipMemcpyDeviceToDevice, stream);
    hipMemcpyAsync(bqkv + DEMB, bK, DEMB * 4, hipMemcpyDeviceToDevice, stream);
    hipMemcpyAsync(bqkv + 2 * DEMB, bV, DEMB * 4, hipMemcpyDeviceToDevice, stream);

    k_qkv<<<dim3(3 * DEMB / 256, SEQ / 256), 512, 0, stream>>>(
        x16, wqkvt, qkv16, bqkv);

    k_scores<<<136, 512, 0, stream>>>(qkv16, sb);

    k_vw_softmax<<<128 + SEQ / 2, 512, 0, stream>>>(qkv16, wot, vwT, sb);

    hipMemsetAsync(out, 0, (size_t)SEQ * DEMB * 4, stream);
    k_pvw<<<dim3(DEMB / 256, SEQ / 256, 2), 512, 0, stream>>>(sb, vwT, out, bO);
}